// Round 6
// baseline (297.232 us; speedup 1.0000x reference)
//
#include <hip/hip_runtime.h>

#define VN 49152
#define DEG 20
#define NB 2
#define MROWS (NB * VN)   // 98304 rows

static constexpr float BN_EPS = 1e-5f;

typedef short bf16x8 __attribute__((ext_vector_type(8)));
typedef float floatx4 __attribute__((ext_vector_type(4)));

__device__ __forceinline__ unsigned short f2bf(float f) {
  unsigned int u = __builtin_bit_cast(unsigned int, f);
  u += 0x7FFFu + ((u >> 16) & 1u);            // RNE
  return (unsigned short)(u >> 16);
}
__device__ __forceinline__ float bf2f(unsigned short h) {
  unsigned int u = ((unsigned int)h) << 16;
  return __builtin_bit_cast(float, u);
}
__device__ __forceinline__ float bflo(unsigned int u) {
  return __builtin_bit_cast(float, u << 16);
}
__device__ __forceinline__ float bfhi(unsigned int u) {
  return __builtin_bit_cast(float, u & 0xFFFF0000u);
}
__device__ __forceinline__ unsigned int packbf(float a, float b) {
  return (unsigned int)f2bf(a) | ((unsigned int)f2bf(b) << 16);
}

// Feature planes (64-ch) stored SWIZZLED as 4 sub-planes [batch][chalf][VN][32]
// addr(b,v,ch) = ((b*2 + ch/32)*VN + v)*32 + ch%32. A combo = 3.15MB -> L2.

// ======================= GEMM1: t1 = x @ W1 + b1 ===========================
// Emits BN sums via one global atomicAdd per channel per block.
#define LDA1 136
__global__ __launch_bounds__(256) void gemm1(const float* __restrict__ X,
    const float* __restrict__ W, const float* __restrict__ bias,
    unsigned short* __restrict__ Y, float* __restrict__ st) {
  __shared__ unsigned short As[128 * LDA1];
  __shared__ unsigned short Bs[64 * LDA1];
  __shared__ float sred[128];
  int t = threadIdx.x;
  int row0 = blockIdx.x * 128;
  if (t < 128) sred[t] = 0.f;
  const float* Xt = X + (size_t)row0 * 128;
  #pragma unroll
  for (int c = 0; c < 16; ++c) {
    int f4i = c * 256 + t;
    int row = f4i >> 5, k = (f4i & 31) * 4;
    float4 v = *(const float4*)(Xt + row * 128 + k);
    *(uint2*)(&As[row * LDA1 + k]) = make_uint2(packbf(v.x, v.y), packbf(v.z, v.w));
  }
  #pragma unroll
  for (int c = 0; c < 32; ++c) {
    int f = c * 256 + t;
    int k = f >> 6, n = f & 63;
    Bs[n * LDA1 + k] = f2bf(W[f]);
  }
  __syncthreads();
  int l = t & 63, wv = t >> 6;
  int lr = l & 15, q = l >> 4;
  int m0 = wv * 32;
  floatx4 acc[2][4];
  #pragma unroll
  for (int mi = 0; mi < 2; ++mi)
    #pragma unroll
    for (int ni = 0; ni < 4; ++ni) acc[mi][ni] = (floatx4)(0.f);
  #pragma unroll
  for (int ks = 0; ks < 128; ks += 32) {
    bf16x8 af[2], bfr[4];
    #pragma unroll
    for (int mi = 0; mi < 2; ++mi)
      af[mi] = *(const bf16x8*)(&As[(m0 + mi * 16 + lr) * LDA1 + ks + q * 8]);
    #pragma unroll
    for (int ni = 0; ni < 4; ++ni)
      bfr[ni] = *(const bf16x8*)(&Bs[(ni * 16 + lr) * LDA1 + ks + q * 8]);
    #pragma unroll
    for (int mi = 0; mi < 2; ++mi)
      #pragma unroll
      for (int ni = 0; ni < 4; ++ni)
        acc[mi][ni] = __builtin_amdgcn_mfma_f32_16x16x32_bf16(af[mi], bfr[ni], acc[mi][ni], 0, 0, 0);
  }
  int b = (row0 >= VN) ? 1 : 0;
  int vbase = row0 - b * VN + m0;
  #pragma unroll
  for (int ni = 0; ni < 4; ++ni) {
    int col = ni * 16 + lr;
    float bv = bias[col];
    size_t sub = (size_t)(b * 2 + (col >> 5)) * VN;
    float s = 0.f, s2 = 0.f;
    #pragma unroll
    for (int mi = 0; mi < 2; ++mi)
      #pragma unroll
      for (int r = 0; r < 4; ++r) {
        float y = acc[mi][ni][r] + bv;
        s += y; s2 += y * y;
        int v = vbase + mi * 16 + q * 4 + r;
        Y[(sub + v) * 32 + (col & 31)] = f2bf(y);
      }
    atomicAdd(&sred[col], s);
    atomicAdd(&sred[64 + col], s2);
  }
  __syncthreads();
  if (t < 128) atomicAdd(&st[t], sred[t]);
}

// ===== GEMM2: t2 = h1@W2[0] + x1@W2[1] + x2@W2[2] + b2 (raw bf16 in) ======
#define LDA2 72
__global__ __launch_bounds__(256) void gemm2(const unsigned short* __restrict__ X0,
    const unsigned short* __restrict__ X1, const unsigned short* __restrict__ X2,
    const float* __restrict__ W, const float* __restrict__ bias,
    unsigned short* __restrict__ Y, float* __restrict__ st) {
  __shared__ unsigned short As[128 * LDA2];
  __shared__ unsigned short Bs[64 * LDA2];
  __shared__ float sred[128];
  int t = threadIdx.x;
  int row0 = blockIdx.x * 128;
  int b = (row0 >= VN) ? 1 : 0;
  int b2 = b * 2;
  int vb0 = row0 - b * VN;
  if (t < 128) sred[t] = 0.f;
  int l = t & 63, wv = t >> 6;
  int lr = l & 15, q = l >> 4;
  int m0 = wv * 32;
  floatx4 acc[2][4];
  #pragma unroll
  for (int mi = 0; mi < 2; ++mi)
    #pragma unroll
    for (int ni = 0; ni < 4; ++ni) acc[mi][ni] = (floatx4)(0.f);

  for (int term = 0; term < 3; ++term) {
    const unsigned short* Xp = (term == 0) ? X0 : (term == 1) ? X1 : X2;
    const float* Wt = W + term * 64 * 64;
    #pragma unroll
    for (int c8 = 0; c8 < 8; ++c8) {
      int i = c8 * 256 + t;
      int row = i >> 4, k = (i & 15) * 4;
      const unsigned short* src = Xp + ((size_t)(b2 + (k >> 5)) * VN + vb0 + row) * 32 + (k & 31);
      *(uint2*)(&As[row * LDA2 + k]) = *(const uint2*)src;
    }
    #pragma unroll
    for (int c = 0; c < 16; ++c) {
      int f = c * 256 + t;
      int k = f >> 6, n = f & 63;
      Bs[n * LDA2 + k] = f2bf(Wt[f]);
    }
    __syncthreads();
    #pragma unroll
    for (int ks = 0; ks < 64; ks += 32) {
      bf16x8 af[2], bfr[4];
      #pragma unroll
      for (int mi = 0; mi < 2; ++mi)
        af[mi] = *(const bf16x8*)(&As[(m0 + mi * 16 + lr) * LDA2 + ks + q * 8]);
      #pragma unroll
      for (int ni = 0; ni < 4; ++ni)
        bfr[ni] = *(const bf16x8*)(&Bs[(ni * 16 + lr) * LDA2 + ks + q * 8]);
      #pragma unroll
      for (int mi = 0; mi < 2; ++mi)
        #pragma unroll
        for (int ni = 0; ni < 4; ++ni)
          acc[mi][ni] = __builtin_amdgcn_mfma_f32_16x16x32_bf16(af[mi], bfr[ni], acc[mi][ni], 0, 0, 0);
    }
    __syncthreads();
  }
  int vbase = vb0 + m0;
  #pragma unroll
  for (int ni = 0; ni < 4; ++ni) {
    int col = ni * 16 + lr;
    float bv = bias[col];
    size_t sub = (size_t)(b2 + (col >> 5)) * VN;
    float s = 0.f, s2 = 0.f;
    #pragma unroll
    for (int mi = 0; mi < 2; ++mi)
      #pragma unroll
      for (int r = 0; r < 4; ++r) {
        float y = acc[mi][ni][r] + bv;
        s += y; s2 += y * y;
        int v = vbase + mi * 16 + q * 4 + r;
        Y[(sub + v) * 32 + (col & 31)] = f2bf(y);
      }
    atomicAdd(&sred[col], s);
    atomicAdd(&sred[64 + col], s2);
  }
  __syncthreads();
  if (t < 128) atomicAdd(&st[t], sred[t]);
}

// ====== GEMM3: t3 = h2 @ W3 + b3; h2 = relu(bn2(t2)) finalized inline ======
__global__ __launch_bounds__(256) void gemm3(const unsigned short* __restrict__ X,
    const float* __restrict__ W, const float* __restrict__ bias,
    const float* __restrict__ st2, const float* __restrict__ gamma,
    const float* __restrict__ beta, unsigned short* __restrict__ Y,
    float* __restrict__ st3) {
  __shared__ unsigned short As[128 * LDA2];
  __shared__ unsigned short Bs[64 * LDA2];
  __shared__ float sred[128];
  __shared__ float scS[64], shS[64];
  int t = threadIdx.x;
  int row0 = blockIdx.x * 128;
  int n0 = blockIdx.y * 64;
  int b = (row0 >= VN) ? 1 : 0;
  int b2 = b * 2;
  int vb0 = row0 - b * VN;
  if (t < 128) sred[t] = 0.f;
  if (t < 64) {                        // finalize bn2 scale/shift inline
    float mean = st2[t] * (1.f / MROWS);
    float var = st2[64 + t] * (1.f / MROWS) - mean * mean;
    float sc = gamma[t] * rsqrtf(var + BN_EPS);
    scS[t] = sc;
    shS[t] = beta[t] - mean * sc;
  }
  __syncthreads();
  #pragma unroll
  for (int c8 = 0; c8 < 8; ++c8) {
    int i = c8 * 256 + t;
    int row = i >> 4, k = (i & 15) * 4;
    const unsigned short* src = X + ((size_t)(b2 + (k >> 5)) * VN + vb0 + row) * 32 + (k & 31);
    uint2 rawv = *(const uint2*)src;
    float y0 = fmaf(bflo(rawv.x), scS[k + 0], shS[k + 0]);
    float y1 = fmaf(bfhi(rawv.x), scS[k + 1], shS[k + 1]);
    float y2 = fmaf(bflo(rawv.y), scS[k + 2], shS[k + 2]);
    float y3 = fmaf(bfhi(rawv.y), scS[k + 3], shS[k + 3]);
    y0 = y0 > 0.f ? y0 : 0.f; y1 = y1 > 0.f ? y1 : 0.f;
    y2 = y2 > 0.f ? y2 : 0.f; y3 = y3 > 0.f ? y3 : 0.f;
    *(uint2*)(&As[row * LDA2 + k]) = make_uint2(packbf(y0, y1), packbf(y2, y3));
  }
  #pragma unroll
  for (int c = 0; c < 16; ++c) {
    int f = c * 256 + t;
    int k = f >> 6, n = f & 63;
    Bs[n * LDA2 + k] = f2bf(W[k * 128 + n0 + n]);
  }
  __syncthreads();
  int l = t & 63, wv = t >> 6;
  int lr = l & 15, q = l >> 4;
  int m0 = wv * 32;
  floatx4 acc[2][4];
  #pragma unroll
  for (int mi = 0; mi < 2; ++mi)
    #pragma unroll
    for (int ni = 0; ni < 4; ++ni) acc[mi][ni] = (floatx4)(0.f);
  #pragma unroll
  for (int ks = 0; ks < 64; ks += 32) {
    bf16x8 af[2], bfr[4];
    #pragma unroll
    for (int mi = 0; mi < 2; ++mi)
      af[mi] = *(const bf16x8*)(&As[(m0 + mi * 16 + lr) * LDA2 + ks + q * 8]);
    #pragma unroll
    for (int ni = 0; ni < 4; ++ni)
      bfr[ni] = *(const bf16x8*)(&Bs[(ni * 16 + lr) * LDA2 + ks + q * 8]);
    #pragma unroll
    for (int mi = 0; mi < 2; ++mi)
      #pragma unroll
      for (int ni = 0; ni < 4; ++ni)
        acc[mi][ni] = __builtin_amdgcn_mfma_f32_16x16x32_bf16(af[mi], bfr[ni], acc[mi][ni], 0, 0, 0);
  }
  #pragma unroll
  for (int ni = 0; ni < 4; ++ni) {
    int lc = ni * 16 + lr;
    int col = n0 + lc;
    float bv = bias[col];
    float s = 0.f, s2 = 0.f;
    #pragma unroll
    for (int mi = 0; mi < 2; ++mi)
      #pragma unroll
      for (int r = 0; r < 4; ++r) {
        float y = acc[mi][ni][r] + bv;
        s += y; s2 += y * y;
        int row = row0 + m0 + mi * 16 + q * 4 + r;
        Y[(size_t)row * 128 + col] = f2bf(y);
      }
    atomicAdd(&sred[lc], s);
    atomicAdd(&sred[64 + lc], s2);
  }
  __syncthreads();
  if (t < 128) atomicAdd(&st3[n0 + ((t >> 6) << 7) + (t & 63)], sred[t]);
}

// -------- bn_h1: h1 = relu(bn1(t1)); bn1 finalized inline ------------------
__global__ __launch_bounds__(256) void bn_h1(const unsigned short* __restrict__ T1,
    const float* __restrict__ st1, const float* __restrict__ gamma,
    const float* __restrict__ beta, unsigned short* __restrict__ H1) {
  __shared__ float scS[64], shS[64];
  int t = threadIdx.x;
  if (t < 64) {
    float mean = st1[t] * (1.f / MROWS);
    float var = st1[64 + t] * (1.f / MROWS) - mean * mean;
    float sc = gamma[t] * rsqrtf(var + BN_EPS);
    scS[t] = sc;
    shS[t] = beta[t] - mean * sc;
  }
  __syncthreads();
  int g = blockIdx.x;
  int combo = (g & 7) >> 1;
  int rg = ((g >> 3) << 1) | (g & 1);
  int wv = t >> 6, lane = t & 63;
  int v = rg * 64 + wv * 16 + (lane >> 2);
  int ch0 = (lane & 3) * 8;
  int cb = (combo & 1) * 32 + ch0;
  size_t off = (size_t)combo * VN * 32 + (size_t)v * 32 + ch0;
  uint4 d = *(const uint4*)(T1 + off);
  float y[8];
  y[0] = fmaf(bflo(d.x), scS[cb + 0], shS[cb + 0]);
  y[1] = fmaf(bfhi(d.x), scS[cb + 1], shS[cb + 1]);
  y[2] = fmaf(bflo(d.y), scS[cb + 2], shS[cb + 2]);
  y[3] = fmaf(bfhi(d.y), scS[cb + 3], shS[cb + 3]);
  y[4] = fmaf(bflo(d.z), scS[cb + 4], shS[cb + 4]);
  y[5] = fmaf(bfhi(d.z), scS[cb + 5], shS[cb + 5]);
  y[6] = fmaf(bflo(d.w), scS[cb + 6], shS[cb + 6]);
  y[7] = fmaf(bfhi(d.w), scS[cb + 7], shS[cb + 7]);
  #pragma unroll
  for (int j = 0; j < 8; ++j) y[j] = y[j] > 0.f ? y[j] : 0.f;
  uint4 o;
  o.x = packbf(y[0], y[1]); o.y = packbf(y[2], y[3]);
  o.z = packbf(y[4], y[5]); o.w = packbf(y[6], y[7]);
  *(uint4*)(H1 + off) = o;
}

// ---------------- spmm1: x1 = L h1  (vectorized neighbor lists) ------------
__global__ __launch_bounds__(256) void spmm1(const unsigned short* __restrict__ H1,
    const int* __restrict__ cols, const float* __restrict__ vals,
    unsigned short* __restrict__ X1out) {
  int g = blockIdx.x;
  int combo = (g & 7) >> 1;
  int rg = ((g >> 3) << 1) | (g & 1);
  int t = threadIdx.x;
  int wv = t >> 6, lane = t & 63;
  int v = rg * 64 + wv * 16 + (lane >> 2);
  int ch0 = (lane & 3) * 8;
  const unsigned short* __restrict__ plane = H1 + (size_t)combo * VN * 32;
  int4  c4[5];
  float4 w4[5];
  const int4*   __restrict__ cp4 = (const int4*)(cols + VN + v * DEG);
  const float4* __restrict__ vp4 = (const float4*)(vals + VN + v * DEG);
  #pragma unroll
  for (int j = 0; j < 5; ++j) { c4[j] = cp4[j]; w4[j] = vp4[j]; }
  float a[8];
  {
    float w0 = vals[v];
    uint4 d = *(const uint4*)(plane + (size_t)v * 32 + ch0);
    a[0] = w0 * bflo(d.x); a[1] = w0 * bfhi(d.x);
    a[2] = w0 * bflo(d.y); a[3] = w0 * bfhi(d.y);
    a[4] = w0 * bflo(d.z); a[5] = w0 * bfhi(d.z);
    a[6] = w0 * bflo(d.w); a[7] = w0 * bfhi(d.w);
  }
  #pragma unroll
  for (int j = 0; j < 5; ++j) {
    const int cj[4] = {c4[j].x, c4[j].y, c4[j].z, c4[j].w};
    const float wj[4] = {w4[j].x, w4[j].y, w4[j].z, w4[j].w};
    #pragma unroll
    for (int e = 0; e < 4; ++e) {
      uint4 d = *(const uint4*)(plane + (size_t)cj[e] * 32 + ch0);
      float w = wj[e];
      a[0] = fmaf(bflo(d.x), w, a[0]); a[1] = fmaf(bfhi(d.x), w, a[1]);
      a[2] = fmaf(bflo(d.y), w, a[2]); a[3] = fmaf(bfhi(d.y), w, a[3]);
      a[4] = fmaf(bflo(d.z), w, a[4]); a[5] = fmaf(bfhi(d.z), w, a[5]);
      a[6] = fmaf(bflo(d.w), w, a[6]); a[7] = fmaf(bfhi(d.w), w, a[7]);
    }
  }
  uint4 o;
  o.x = packbf(a[0], a[1]); o.y = packbf(a[2], a[3]);
  o.z = packbf(a[4], a[5]); o.w = packbf(a[6], a[7]);
  *(uint4*)(X1out + (size_t)combo * VN * 32 + (size_t)v * 32 + ch0) = o;
}

// ------------- spmm2: x2 = 2*(L x1) - h1 -----------------------------------
__global__ __launch_bounds__(256) void spmm2(const unsigned short* __restrict__ X1,
    const unsigned short* __restrict__ H1, const int* __restrict__ cols,
    const float* __restrict__ vals, unsigned short* __restrict__ X2out) {
  int g = blockIdx.x;
  int combo = (g & 7) >> 1;
  int rg = ((g >> 3) << 1) | (g & 1);
  int t = threadIdx.x;
  int wv = t >> 6, lane = t & 63;
  int v = rg * 64 + wv * 16 + (lane >> 2);
  int ch0 = (lane & 3) * 8;
  const size_t pbase = (size_t)combo * VN * 32;
  const size_t myoff = pbase + (size_t)v * 32 + ch0;
  const unsigned short* __restrict__ plane = X1 + pbase;
  int4  c4[5];
  float4 w4[5];
  const int4*   __restrict__ cp4 = (const int4*)(cols + VN + v * DEG);
  const float4* __restrict__ vp4 = (const float4*)(vals + VN + v * DEG);
  #pragma unroll
  for (int j = 0; j < 5; ++j) { c4[j] = cp4[j]; w4[j] = vp4[j]; }
  float a[8];
  {
    float w0 = vals[v];
    uint4 d = *(const uint4*)(X1 + myoff);
    a[0] = w0 * bflo(d.x); a[1] = w0 * bfhi(d.x);
    a[2] = w0 * bflo(d.y); a[3] = w0 * bfhi(d.y);
    a[4] = w0 * bflo(d.z); a[5] = w0 * bfhi(d.z);
    a[6] = w0 * bflo(d.w); a[7] = w0 * bfhi(d.w);
  }
  #pragma unroll
  for (int j = 0; j < 5; ++j) {
    const int cj[4] = {c4[j].x, c4[j].y, c4[j].z, c4[j].w};
    const float wj[4] = {w4[j].x, w4[j].y, w4[j].z, w4[j].w};
    #pragma unroll
    for (int e = 0; e < 4; ++e) {
      uint4 d = *(const uint4*)(plane + (size_t)cj[e] * 32 + ch0);
      float w = wj[e];
      a[0] = fmaf(bflo(d.x), w, a[0]); a[1] = fmaf(bfhi(d.x), w, a[1]);
      a[2] = fmaf(bflo(d.y), w, a[2]); a[3] = fmaf(bfhi(d.y), w, a[3]);
      a[4] = fmaf(bflo(d.z), w, a[4]); a[5] = fmaf(bfhi(d.z), w, a[5]);
      a[6] = fmaf(bflo(d.w), w, a[6]); a[7] = fmaf(bfhi(d.w), w, a[7]);
    }
  }
  uint4 h = *(const uint4*)(H1 + myoff);
  uint4 o;
  o.x = packbf(2.f * a[0] - bflo(h.x), 2.f * a[1] - bfhi(h.x));
  o.y = packbf(2.f * a[2] - bflo(h.y), 2.f * a[3] - bfhi(h.y));
  o.z = packbf(2.f * a[4] - bflo(h.z), 2.f * a[5] - bfhi(h.z));
  o.w = packbf(2.f * a[6] - bflo(h.w), 2.f * a[7] - bfhi(h.w));
  *(uint4*)(X2out + myoff) = o;
}

// --------- final: out = relu(bn3(t3)) fp32; bn3 finalized inline -----------
__global__ __launch_bounds__(256) void bn_final(const unsigned short* __restrict__ T,
    float* __restrict__ Y, const float* __restrict__ st3,
    const float* __restrict__ gamma, const float* __restrict__ beta) {
  __shared__ float scS[128], shS[128];
  int t = threadIdx.x;
  if (t < 128) {
    float mean = st3[t] * (1.f / MROWS);
    float var = st3[128 + t] * (1.f / MROWS) - mean * mean;
    float sc = gamma[t] * rsqrtf(var + BN_EPS);
    scS[t] = sc;
    shS[t] = beta[t] - mean * sc;
  }
  __syncthreads();
  size_t i4 = ((size_t)blockIdx.x * 256 + t) * 4;
  int c0 = (int)(i4 & 127);
  ushort4 tv = *(const ushort4*)(T + i4);
  unsigned short sv[4] = {tv.x, tv.y, tv.z, tv.w};
  float ov[4];
  #pragma unroll
  for (int j = 0; j < 4; ++j) {
    int c = c0 + j;
    float y = fmaf(bf2f(sv[j]), scS[c], shS[c]);
    ov[j] = y > 0.f ? y : 0.f;
  }
  *(float4*)(Y + i4) = make_float4(ov[0], ov[1], ov[2], ov[3]);
}

extern "C" void kernel_launch(void* const* d_in, const int* in_sizes, int n_in,
                              void* d_out, int out_size, void* d_ws, size_t ws_size,
                              hipStream_t stream) {
  const float* x    = (const float*)d_in[0];
  const int*   cols = (const int*)  d_in[2];
  const float* vals = (const float*)d_in[3];
  const float* W1   = (const float*)d_in[4];
  const float* b1   = (const float*)d_in[5];
  const float* g1   = (const float*)d_in[6];
  const float* be1  = (const float*)d_in[7];
  const float* W2   = (const float*)d_in[8];
  const float* b2   = (const float*)d_in[9];
  const float* g2   = (const float*)d_in[10];
  const float* be2  = (const float*)d_in[11];
  const float* W3   = (const float*)d_in[12];
  const float* b3   = (const float*)d_in[13];
  const float* g3   = (const float*)d_in[14];
  const float* be3  = (const float*)d_in[15];
  float* out = (float*)d_out;

  const size_t PL = (size_t)MROWS * 64;          // plane elements
  unsigned short* P0 = (unsigned short*)d_ws;    // t1, then t2
  unsigned short* PH = P0 + PL;                  // h1
  unsigned short* P1 = PH + PL;                  // x1
  unsigned short* P2 = P1 + PL;                  // x2, then t3 [MROWS,128]
  float* st1 = (float*)(P2 + 2 * PL);            // 128
  float* st2 = st1 + 128;                        // 128
  float* st3 = st2 + 128;                        // 256

  hipMemsetAsync(st1, 0, 512 * sizeof(float), stream);

  dim3 blk(256);
  int rowb = MROWS / 128;                        // 768
  int spmm_blocks = 3072;                        // 64 rows x 4 combos
  int ap128_blocks = (int)(PL * 2 / 4 / 256);    // 12288

  // Layer 1
  gemm1<<<rowb, blk, 0, stream>>>(x, W1, b1, P0, st1);
  bn_h1<<<spmm_blocks, blk, 0, stream>>>(P0, st1, g1, be1, PH);

  // Layer 2 (K=3 Chebyshev)
  spmm1<<<spmm_blocks, blk, 0, stream>>>(PH, cols, vals, P1);
  spmm2<<<spmm_blocks, blk, 0, stream>>>(P1, PH, cols, vals, P2);
  gemm2<<<rowb, blk, 0, stream>>>(PH, P1, P2, W2, b2, P0, st2);    // t2 -> P0

  // Layer 3
  dim3 g3grid(rowb, 2);
  gemm3<<<g3grid, blk, 0, stream>>>(P0, W3, b3, st2, g2, be2, P2, st3);
  bn_final<<<ap128_blocks, blk, 0, stream>>>(P2, out, st3, g3, be3);
}